// Round 4
// baseline (242.563 us; speedup 1.0000x reference)
//
#include <hip/hip_runtime.h>
#include <math.h>

// SoftGlidingBoxes: for each (b, ch=c*8+l) 256x256 image and scale s=1..8,
// sum over valid positions of the s x s sliding-window max, then relu(.)+1.
// x: [16, 256, 256, 3, 8] fp32 -> out: [16, 3, 8, 8] fp32.
//
// Round-4: single pass. Register DP
//   M_s[i][j] = max(M_{s-1} at (i,j),(i,j+1),(i+1,j),(i+1,j+1))
// marching rows bottom-to-top. Per thread (ch, 8-col strip) per row:
//   2 coalesced float4 global loads (staging role, col-pair of 8 ch),
//   4 ds_write_b32 (bf16-packed col pairs), 4 ds_read_b32, 7 ds_bpermute
//   (right-neighbor halo; prev-row halo cached in nbP[] registers).
// 256-thread blocks (8 ch x 32 strips): 3-4 independent blocks/CU so the
// per-row __syncthreads only stalls a fraction of the CU.

namespace {
constexpr int Bn = 16, Hn = 256, Wn = 256, CHn = 24, Sn = 8;
constexpr int IT = 16, NBANDS = Hn / IT;   // 16 bands of 16 output rows
constexpr int CHG = 3;                     // channel groups of 8
constexpr int BDIM = 256;                  // 8 ch x 32 strips = 4 waves
// LDS: bf16 col-pairs, addr(c8, cp) = c8*144 + cp + 5*(cp>>5), cp<128.
// Reads (cp = 4*strip+k) hit all 32 banks exactly once per k: conflict-free.
constexpr int LSTR = 144;
constexpr int LROW = 8 * LSTR;             // 1152 dwords per buffer
constexpr int OUT_N = Bn * CHn * Sn;       // 3072
}

__device__ __forceinline__ unsigned bf16pack2(float a, float b) {  // RTNE
  unsigned ua = __float_as_uint(a), ub = __float_as_uint(b);
  ua = (ua + 0x7FFFu + ((ua >> 16) & 1u)) >> 16;
  ub = (ub + 0x7FFFu + ((ub >> 16) & 1u)) & 0xFFFF0000u;
  return ua | ub;
}

__global__ __launch_bounds__(BDIM, 4) void sgb_main(const float* __restrict__ x,
                                                    float* __restrict__ accum) {
  __shared__ unsigned buf[2][LROW];

  const int cg   = blockIdx.x;            // 0..2 (fastest: sibling cg blocks
  const int band = blockIdx.y;            //        co-resident -> L2 sharing)
  const int b    = blockIdx.z;
  const int i0   = band * IT;
  const int tid  = threadIdx.x;

  // compute role: (chl, strip) — 8 local ch x 32 strips of 8 cols
  const int chl = tid >> 5, strip = tid & 31;
  const int ch  = cg * 8 + chl;
  const int rb0 = chl * LSTR;             // + (4*strip+k) + 5*((4*strip+k)>>5)

  // staging role: col-pair cp2 (cols 2*cp2, 2*cp2+1), ch half chh..chh+3
  const int cp2 = tid & 127;
  const int chh = (tid >> 7) * 4;
  const int wsw = cp2 + 5 * (cp2 >> 5);   // swizzled col-pair offset

  float P[7][8];                          // prev-row M_1..M_7, own 8 cols
#pragma unroll
  for (int s = 0; s < 7; ++s)
#pragma unroll
    for (int j = 0; j < 8; ++j) P[s][j] = -INFINITY;
  float nbP[7];                           // prev-row M_s[col 8] (halo cache)
#pragma unroll
  for (int s = 0; s < 7; ++s) nbP[s] = -INFINITY;
  float acc[Sn];
#pragma unroll
  for (int s = 0; s < Sn; ++s) acc[s] = 0.f;

  const float* img = x + ((long)b * Hn) * (Wn * CHn) + cg * 8 + chh;
  const int rhi = i0 + IT + 6;            // topmost consumed row

  // Prologue: stage row rhi into buf[0].
  if (rhi < Hn) {
    const float* src = img + ((long)rhi * Wn + 2 * cp2) * CHn;
    const float4 v0 = reinterpret_cast<const float4*>(src)[0];
    const float4 v1 = reinterpret_cast<const float4*>(src + CHn)[0];
    unsigned* d = &buf[0][chh * LSTR + wsw];
    d[0 * LSTR] = bf16pack2(v0.x, v1.x);
    d[1 * LSTR] = bf16pack2(v0.y, v1.y);
    d[2 * LSTR] = bf16pack2(v0.z, v1.z);
    d[3 * LSTR] = bf16pack2(v0.w, v1.w);
  }

  for (int idx = 0; idx < IT + 7; ++idx) {
    const int r  = rhi - idx;
    const int pb = idx & 1;
    __syncthreads();                      // row r staged & visible

    // Prefetch next row's global data (LDS-write deferred to loop end).
    const bool do_stage = (idx < IT + 6) && (r - 1 < Hn);
    float4 v0, v1;
    if (do_stage) {
      const float* src = img + ((long)(r - 1) * Wn + 2 * cp2) * CHn;
      v0 = reinterpret_cast<const float4*>(src)[0];
      v1 = reinterpret_cast<const float4*>(src + CHn)[0];
    }

    float cp[8];                          // M_1[r] at own 8 cols
    if (r < Hn) {
#pragma unroll
      for (int k = 0; k < 4; ++k) {
        const int c = 4 * strip + k;
        const unsigned d = buf[pb][rb0 + c + 5 * (c >> 5)];
        cp[2 * k]     = __uint_as_float(d << 16);
        cp[2 * k + 1] = __uint_as_float(d & 0xFFFF0000u);
      }
    } else {
#pragma unroll
      for (int k = 0; k < 8; ++k) cp[k] = -INFINITY;
    }

    const bool outrow = (r < i0 + IT);    // r >= i0 always holds
    if (outrow) {                         // s=1: all 256 window starts valid
      acc[0] += ((cp[0] + cp[1]) + (cp[2] + cp[3])) +
                ((cp[4] + cp[5]) + (cp[6] + cp[7]));
    }

#pragma unroll
    for (int s = 2; s <= Sn; ++s) {
      // col-8 halo = right neighbor's col 0 (lane+1, same chl for strip<31).
      // strip 31's pull is garbage but lands only in windows with j+s>8,
      // exactly the invalid (col+s>256) ones -> masked below.
      const float nbNew = __shfl_down(cp[0], 1);
      const float nbOld = nbP[s - 2];
      nbP[s - 2] = nbNew;
      float cc[8];
#pragma unroll
      for (int j = 0; j < 7; ++j)
        cc[j] = fmaxf(fmaxf(cp[j], cp[j + 1]),
                      fmaxf(P[s - 2][j], P[s - 2][j + 1]));
      cc[7] = fmaxf(fmaxf(cp[7], nbNew), fmaxf(P[s - 2][7], nbOld));

      if (outrow && (r + s <= Hn)) {
        float lo = 0.f, hi = 0.f;         // hi: windows spilling past col 8-s
#pragma unroll
        for (int j = 0; j < 8; ++j) {
          if (j <= 8 - s) lo += cc[j]; else hi += cc[j];
        }
        acc[s - 1] += lo + (strip == 31 ? 0.f : hi);
      }
#pragma unroll
      for (int j = 0; j < 8; ++j) { P[s - 2][j] = cp[j]; cp[j] = cc[j]; }
    }

    if (do_stage) {
      unsigned* d = &buf[pb ^ 1][chh * LSTR + wsw];
      d[0 * LSTR] = bf16pack2(v0.x, v1.x);
      d[1 * LSTR] = bf16pack2(v0.y, v1.y);
      d[2 * LSTR] = bf16pack2(v0.z, v1.z);
      d[3 * LSTR] = bf16pack2(v0.w, v1.w);
    }
  }

  // Reduce 32 strips per ch (xor net stays inside each 32-lane half-wave).
#pragma unroll
  for (int s = 0; s < Sn; ++s) {
    float v = acc[s];
    v += __shfl_xor(v, 16);
    v += __shfl_xor(v, 8);
    v += __shfl_xor(v, 4);
    v += __shfl_xor(v, 2);
    v += __shfl_xor(v, 1);
    if (strip == 0) atomicAdd(&accum[(b * CHn + ch) * Sn + s], v);
  }
}

__global__ void sgb_finalize(float* __restrict__ out) {
  const int i = blockIdx.x * blockDim.x + threadIdx.x;
  if (i < OUT_N) out[i] = fmaxf(out[i], 0.f) + 1.f;
}

extern "C" void kernel_launch(void* const* d_in, const int* in_sizes, int n_in,
                              void* d_out, int out_size, void* d_ws, size_t ws_size,
                              hipStream_t stream) {
  (void)in_sizes; (void)n_in; (void)d_ws; (void)ws_size; (void)out_size;
  const float* x = (const float*)d_in[0];
  float* out = (float*)d_out;

  hipMemsetAsync(out, 0, OUT_N * sizeof(float), stream);
  dim3 grid(CHG, NBANDS, Bn);            // 3 x 16 x 16 = 768 blocks x 256 thr
  sgb_main<<<grid, BDIM, 0, stream>>>(x, out);
  sgb_finalize<<<(OUT_N + 255) / 256, 256, 0, stream>>>(out);
}

// Round 5
// 205.311 us; speedup vs baseline: 1.1814x; 1.1814x over previous
//
#include <hip/hip_runtime.h>
#include <math.h>

// SoftGlidingBoxes: for each (b, ch=c*8+l) 256x256 image and scale s=1..8,
// sum over valid positions of the s x s sliding-window max, then relu(.)+1.
// x: [16, 256, 256, 3, 8] fp32 -> out: [16, 3, 8, 8] fp32.
//
// Round-5: register DP  M_s[i][j] = max(M_{s-1} @ (i,j),(i,j+1),(i+1,j),(i+1,j+1))
// marching rows bottom-to-top. 384-thread blocks = 12 ch x 32 strips(8 cols);
// per thread-row: 4 ds_read_b32 (bf16-packed pairs), 4 ds_write_b32,
// 7 ds_bpermute (halo; prev-row halo cached in nbP regs). No cc[] temp array
// (in-place rotation) -> ~90 VGPR, NO SPILLS (round-4 killer: 149 MB scratch).
// IT=8 -> 1024 blocks, ~3 blocks/CU so barriers/loads overlap across blocks.

namespace {
constexpr int Bn = 16, Hn = 256, Wn = 256, CHn = 24, Sn = 8;
constexpr int IT = 8;                      // output rows per band
constexpr int NBANDS = Hn / IT;            // 32
constexpr int BDIM = 384;                  // 12 ch x 32 strips = 6 waves
// LDS: bf16 col-pair words, addr(chl, m) = chl*144 + m + 5*(m>>5), m<128.
// Compute reads (m=4*strip+k): per k the 4 strip-octants cover banks
// {k+4t},{k+5+4t},{k+10+4t},{k+15+4t} = all 32; other ch-half +16 shift.
// 2 lanes/bank = free (m136). Writes: consecutive m -> 2/bank, free.
constexpr int LSTR = 144;
constexpr int LWORDS = 12 * LSTR;          // 1728 words per buffer (6.9 KB)
constexpr int OUT_N = Bn * CHn * Sn;       // 3072
}

__device__ __forceinline__ unsigned bf16pack2(float a, float b) {  // RTNE
  unsigned ua = __float_as_uint(a), ub = __float_as_uint(b);
  ua = (ua + 0x7FFFu + ((ua >> 16) & 1u)) >> 16;
  ub = (ub + 0x7FFFu + ((ub >> 16) & 1u)) & 0xFFFF0000u;
  return ua | ub;
}

__global__ __launch_bounds__(BDIM, 3) void sgb_main(const float* __restrict__ x,
                                                    float* __restrict__ accum) {
  __shared__ unsigned buf[2][LWORDS];

  // 1-D grid decode: cg-sibling blocks differ by 8 in linear ID -> same XCD
  // under round-robin dispatch -> complementary line-halves hit in L2.
  const int lin = blockIdx.x;               // 0..1023
  const int cg   = (lin >> 3) & 1;          // channel half: ch cg*12..cg*12+11
  const int u    = ((lin >> 4) << 3) | (lin & 7);  // 0..511
  const int band = u & 31;
  const int b    = u >> 5;
  const int i0   = band * IT;
  const int tid  = threadIdx.x;

  // compute role: (chl, strip) — 12 local ch x 32 strips of 8 cols
  const int chl = tid >> 5, strip = tid & 31;
  const int ch  = cg * 12 + chl;
  const int rb0 = chl * LSTR;

  // staging role: col-pair m (cols 2m, 2m+1), ch quad h..h+3
  const int m   = tid & 127;
  const int h   = (tid >> 7) * 4;           // 0,4,8
  const int wsw = m + 5 * (m >> 5);         // swizzled word offset

  float P[7][8];                            // prev-row M_1..M_7, own 8 cols
#pragma unroll
  for (int s = 0; s < 7; ++s)
#pragma unroll
    for (int j = 0; j < 8; ++j) P[s][j] = -INFINITY;
  float nbP[7];                             // prev-row M_s[col 8] halo cache
#pragma unroll
  for (int s = 0; s < 7; ++s) nbP[s] = -INFINITY;
  float acc[Sn];
#pragma unroll
  for (int s = 0; s < Sn; ++s) acc[s] = 0.f;

  const float* img = x + ((long)b * Hn) * (Wn * CHn) + cg * 12 + h;
  const int rhi = i0 + IT + 6;              // topmost consumed row

  // Prologue: stage row rhi into buf[0] (all 384 threads, 4 packed words).
  if (rhi < Hn) {
    const float* src = img + ((long)rhi * Wn + 2 * m) * CHn;
    const float4 v0 = reinterpret_cast<const float4*>(src)[0];
    const float4 v1 = reinterpret_cast<const float4*>(src + CHn)[0];
    unsigned* d = &buf[0][h * LSTR + wsw];
    d[0 * LSTR] = bf16pack2(v0.x, v1.x);
    d[1 * LSTR] = bf16pack2(v0.y, v1.y);
    d[2 * LSTR] = bf16pack2(v0.z, v1.z);
    d[3 * LSTR] = bf16pack2(v0.w, v1.w);
  }

  for (int idx = 0; idx < IT + 7; ++idx) {
    const int r  = rhi - idx;
    const int pb = idx & 1;
    __syncthreads();                        // row r staged & visible

    // Prefetch next row's global data; pack+LDS-write after compute.
    const bool do_stage = (idx < IT + 6) && (r - 1 < Hn);
    float4 v0, v1;
    if (do_stage) {
      const float* src = img + ((long)(r - 1) * Wn + 2 * m) * CHn;
      v0 = reinterpret_cast<const float4*>(src)[0];
      v1 = reinterpret_cast<const float4*>(src + CHn)[0];
    }

    float cp[8];                            // M_1[r] at own 8 cols
    if (r < Hn) {
#pragma unroll
      for (int k = 0; k < 4; ++k) {
        const int c = 4 * strip + k;
        const unsigned d = buf[pb][rb0 + c + 5 * (c >> 5)];
        cp[2 * k]     = __uint_as_float(d << 16);
        cp[2 * k + 1] = __uint_as_float(d & 0xFFFF0000u);
      }
    } else {
#pragma unroll
      for (int k = 0; k < 8; ++k) cp[k] = -INFINITY;
    }

    const bool outrow = (r < i0 + IT);      // r >= i0 always holds
    if (outrow) {                           // s=1: all 256 window starts valid
      acc[0] += ((cp[0] + cp[1]) + (cp[2] + cp[3])) +
                ((cp[4] + cp[5]) + (cp[6] + cp[7]));
    }

#pragma unroll
    for (int s = 2; s <= Sn; ++s) {
      // col-8 halo = lane+1's col 0. strip 31's pull is garbage but lands
      // only in windows with j+s>8 == exactly the invalid ones -> masked.
      const float nbNew = __shfl_down(cp[0], 1);
      const float nbOld = nbP[s - 2];
      nbP[s - 2] = nbNew;
      // In-place update (no cc[] array): a carries old cp[j].
      float a = cp[0];
#pragma unroll
      for (int j = 0; j < 7; ++j) {
        const float t = cp[j + 1];
        cp[j] = fmaxf(fmaxf(a, t), fmaxf(P[s - 2][j], P[s - 2][j + 1]));
        P[s - 2][j] = a;
        a = t;
      }
      cp[7] = fmaxf(fmaxf(a, nbNew), fmaxf(P[s - 2][7], nbOld));
      P[s - 2][7] = a;

      if (outrow && (r + s <= Hn)) {
        float lo = 0.f, hi = 0.f;           // hi: windows spilling past col 8-s
#pragma unroll
        for (int j = 0; j < 8; ++j) {
          if (j <= 8 - s) lo += cp[j]; else hi += cp[j];
        }
        acc[s - 1] += lo + (strip == 31 ? 0.f : hi);
      }
    }

    if (do_stage) {
      unsigned* d = &buf[pb ^ 1][h * LSTR + wsw];
      d[0 * LSTR] = bf16pack2(v0.x, v1.x);
      d[1 * LSTR] = bf16pack2(v0.y, v1.y);
      d[2 * LSTR] = bf16pack2(v0.z, v1.z);
      d[3 * LSTR] = bf16pack2(v0.w, v1.w);
    }
  }

  // Reduce 32 strips per ch. Wave = 2 ch x 32 strips; xor<32 stays in-half.
#pragma unroll
  for (int s = 0; s < Sn; ++s) {
    float v = acc[s];
    v += __shfl_xor(v, 16);
    v += __shfl_xor(v, 8);
    v += __shfl_xor(v, 4);
    v += __shfl_xor(v, 2);
    v += __shfl_xor(v, 1);
    if (strip == 0) atomicAdd(&accum[(b * CHn + ch) * Sn + s], v);
  }
}

__global__ void sgb_finalize(float* __restrict__ out) {
  const int i = blockIdx.x * blockDim.x + threadIdx.x;
  if (i < OUT_N) out[i] = fmaxf(out[i], 0.f) + 1.f;
}

extern "C" void kernel_launch(void* const* d_in, const int* in_sizes, int n_in,
                              void* d_out, int out_size, void* d_ws, size_t ws_size,
                              hipStream_t stream) {
  (void)in_sizes; (void)n_in; (void)d_ws; (void)ws_size; (void)out_size;
  const float* x = (const float*)d_in[0];
  float* out = (float*)d_out;

  hipMemsetAsync(out, 0, OUT_N * sizeof(float), stream);
  sgb_main<<<dim3(2 * NBANDS * Bn), BDIM, 0, stream>>>(x, out);  // 1024 blocks
  sgb_finalize<<<(OUT_N + 255) / 256, 256, 0, stream>>>(out);
}

// Round 6
// 166.512 us; speedup vs baseline: 1.4567x; 1.2330x over previous
//
#include <hip/hip_runtime.h>
#include <math.h>

// SoftGlidingBoxes: for each (b, ch=c*8+l) 256x256 image and scale s=1..8,
// sum over valid positions of the s x s sliding-window max, then relu(.)+1.
// x: [16, 256, 256, 3, 8] fp32 -> out: [16, 3, 8, 8] fp32.
//
// Round-6: register DP  M_s[i][j] = max(M_{s-1} @ (i,j),(i,j+1),(i+1,j),(i+1,j+1))
// marching rows bottom-to-top.
//  - 256-thread blocks = 8 ch x 32 strips(8 cols); cg in {0,1,2} picks the
//    channel group; IT=16 output rows/band -> 23/16 = 1.44x halo overhead.
//  - TWO-iteration global prefetch: row r-2 is loaded while computing row r;
//    the register-held row r-1 is LDS-written after compute. Load-to-use
//    slack ~1.5 iterations (vs ~0.5 in R5, which plateaued at 99 us /
//    VALUBusy 45% = latency-bound at the per-row barrier).
//  - Grid swizzle puts the 3 cg-siblings (sharing input lines) on the same
//    XCD under round-robin dispatch.

namespace {
constexpr int Bn = 16, Hn = 256, Wn = 256, CHn = 24, Sn = 8;
constexpr int IT = 16;                     // output rows per band
constexpr int NBANDS = Hn / IT;            // 16
constexpr int BDIM = 256;                  // 8 ch x 32 strips = 4 waves
constexpr int NBLK = 3 * NBANDS * Bn;      // 768
// LDS: bf16 col-pair words, addr(chl, m) = chl*144 + m + 5*(m>>5), m<128.
// Compute reads (m=4*strip+k) hit all 32 banks <=2 lanes each: free (m136).
constexpr int LSTR = 144;
constexpr int LWORDS = 8 * LSTR;           // 1152 words per buffer (4.6 KB)
constexpr int OUT_N = Bn * CHn * Sn;       // 3072
}

__device__ __forceinline__ unsigned bf16pack2(float a, float b) {  // RTNE
  unsigned ua = __float_as_uint(a), ub = __float_as_uint(b);
  ua = (ua + 0x7FFFu + ((ua >> 16) & 1u)) >> 16;
  ub = (ub + 0x7FFFu + ((ub >> 16) & 1u)) & 0xFFFF0000u;
  return ua | ub;
}

__global__ __launch_bounds__(BDIM, 3) void sgb_main(const float* __restrict__ x,
                                                    float* __restrict__ accum) {
  __shared__ unsigned buf[2][LWORDS];

  // lin = (g/8)*24 + cg*8 + g%8, g = band*16 + b. All 3 cg-siblings of a
  // given g share lin%8 -> same XCD under round-robin -> L2 line sharing.
  const int lin = blockIdx.x;               // 0..767
  const int q   = lin / 24;                 // g/8
  const int rem = lin - q * 24;
  const int cg  = rem >> 3;                 // 0..2
  const int g   = q * 8 + (rem & 7);        // 0..255
  const int band = g >> 4;
  const int b    = g & 15;
  const int i0   = band * IT;
  const int tid  = threadIdx.x;

  // compute role: (chl, strip) — 8 local ch x 32 strips of 8 cols
  const int chl = tid >> 5, strip = tid & 31;
  const int ch  = cg * 8 + chl;
  const int rb0 = chl * LSTR;

  // staging role: col-pair m (cols 2m, 2m+1), ch quad h..h+3 (h = 0 or 4)
  const int m   = tid & 127;
  const int h   = (tid >> 7) * 4;
  const int wsw = m + 5 * (m >> 5);         // swizzled word offset

  float P[7][8];                            // prev-row M_1..M_7, own 8 cols
#pragma unroll
  for (int s = 0; s < 7; ++s)
#pragma unroll
    for (int j = 0; j < 8; ++j) P[s][j] = -INFINITY;
  float nbP[7];                             // prev-row M_s[col 8] halo cache
#pragma unroll
  for (int s = 0; s < 7; ++s) nbP[s] = -INFINITY;
  float acc[Sn];
#pragma unroll
  for (int s = 0; s < Sn; ++s) acc[s] = 0.f;

  const float* img = x + ((long)b * Hn) * (Wn * CHn) + cg * 8 + h;
  const int rhi = i0 + IT + 6;              // topmost consumed row

  // Prologue: row rhi -> buf[0]; row rhi-1 -> in-flight regs.
  float4 v0, v1;                            // row r-1 (to write this iter)
  if (rhi < Hn) {
    const float* src = img + ((long)rhi * Wn + 2 * m) * CHn;
    const float4 a0 = reinterpret_cast<const float4*>(src)[0];
    const float4 a1 = reinterpret_cast<const float4*>(src + CHn)[0];
    unsigned* d = &buf[0][h * LSTR + wsw];
    d[0 * LSTR] = bf16pack2(a0.x, a1.x);
    d[1 * LSTR] = bf16pack2(a0.y, a1.y);
    d[2 * LSTR] = bf16pack2(a0.z, a1.z);
    d[3 * LSTR] = bf16pack2(a0.w, a1.w);
  }
  if (rhi - 1 >= 0 && rhi - 1 < Hn) {
    const float* src = img + ((long)(rhi - 1) * Wn + 2 * m) * CHn;
    v0 = reinterpret_cast<const float4*>(src)[0];
    v1 = reinterpret_cast<const float4*>(src + CHn)[0];
  }

  for (int idx = 0; idx < IT + 7; ++idx) {
    const int r  = rhi - idx;
    const int pb = idx & 1;
    __syncthreads();                        // buf[pb] holds row r

    // Issue load of row r-2 (consumed at iter idx+2) — ~1.5 iters of slack.
    float4 n0, n1;
    const bool do_load = (idx < IT + 5) && (unsigned)(r - 2) < (unsigned)Hn;
    if (do_load) {
      const float* src = img + ((long)(r - 2) * Wn + 2 * m) * CHn;
      n0 = reinterpret_cast<const float4*>(src)[0];
      n1 = reinterpret_cast<const float4*>(src + CHn)[0];
    }

    float cp[8];                            // M_1[r] at own 8 cols
    if (r < Hn) {
#pragma unroll
      for (int k = 0; k < 4; ++k) {
        const int c = 4 * strip + k;
        const unsigned d = buf[pb][rb0 + c + 5 * (c >> 5)];
        cp[2 * k]     = __uint_as_float(d << 16);
        cp[2 * k + 1] = __uint_as_float(d & 0xFFFF0000u);
      }
    } else {
#pragma unroll
      for (int k = 0; k < 8; ++k) cp[k] = -INFINITY;
    }

    const bool outrow = (r < i0 + IT);      // r >= i0 always holds
    if (outrow) {                           // s=1: all 256 window starts valid
      acc[0] += ((cp[0] + cp[1]) + (cp[2] + cp[3])) +
                ((cp[4] + cp[5]) + (cp[6] + cp[7]));
    }

#pragma unroll
    for (int s = 2; s <= Sn; ++s) {
      // col-8 halo = lane+1's col 0. strip 31's pull is garbage but lands
      // only in windows with j+s>8 == exactly the invalid ones -> masked.
      const float nbNew = __shfl_down(cp[0], 1);
      const float nbOld = nbP[s - 2];
      nbP[s - 2] = nbNew;
      float a = cp[0];                      // in-place rotation, no cc[] array
#pragma unroll
      for (int j = 0; j < 7; ++j) {
        const float t = cp[j + 1];
        cp[j] = fmaxf(fmaxf(a, t), fmaxf(P[s - 2][j], P[s - 2][j + 1]));
        P[s - 2][j] = a;
        a = t;
      }
      cp[7] = fmaxf(fmaxf(a, nbNew), fmaxf(P[s - 2][7], nbOld));
      P[s - 2][7] = a;

      if (outrow && (r + s <= Hn)) {
        float lo = 0.f, hi = 0.f;           // hi: windows spilling past col 8-s
#pragma unroll
        for (int j = 0; j < 8; ++j) {
          if (j <= 8 - s) lo += cp[j]; else hi += cp[j];
        }
        acc[s - 1] += lo + (strip == 31 ? 0.f : hi);
      }
    }

    // LDS-write row r-1 (regs loaded at iter idx-1) into buf[pb^1].
    const bool do_write = (idx < IT + 6) && (unsigned)(r - 1) < (unsigned)Hn;
    if (do_write) {
      unsigned* d = &buf[pb ^ 1][h * LSTR + wsw];
      d[0 * LSTR] = bf16pack2(v0.x, v1.x);
      d[1 * LSTR] = bf16pack2(v0.y, v1.y);
      d[2 * LSTR] = bf16pack2(v0.z, v1.z);
      d[3 * LSTR] = bf16pack2(v0.w, v1.w);
    }
    v0 = n0; v1 = n1;
  }

  // Reduce 32 strips per ch. Wave = 2 ch x 32 strips; xor<32 stays in-half.
#pragma unroll
  for (int s = 0; s < Sn; ++s) {
    float v = acc[s];
    v += __shfl_xor(v, 16);
    v += __shfl_xor(v, 8);
    v += __shfl_xor(v, 4);
    v += __shfl_xor(v, 2);
    v += __shfl_xor(v, 1);
    if (strip == 0) atomicAdd(&accum[(b * CHn + ch) * Sn + s], v);
  }
}

__global__ void sgb_finalize(float* __restrict__ out) {
  const int i = blockIdx.x * blockDim.x + threadIdx.x;
  if (i < OUT_N) out[i] = fmaxf(out[i], 0.f) + 1.f;
}

extern "C" void kernel_launch(void* const* d_in, const int* in_sizes, int n_in,
                              void* d_out, int out_size, void* d_ws, size_t ws_size,
                              hipStream_t stream) {
  (void)in_sizes; (void)n_in; (void)d_ws; (void)ws_size; (void)out_size;
  const float* x = (const float*)d_in[0];
  float* out = (float*)d_out;

  hipMemsetAsync(out, 0, OUT_N * sizeof(float), stream);
  sgb_main<<<dim3(NBLK), BDIM, 0, stream>>>(x, out);   // 768 blocks x 256 thr
  sgb_finalize<<<(OUT_N + 255) / 256, 256, 0, stream>>>(out);
}

// Round 7
// 165.747 us; speedup vs baseline: 1.4635x; 1.0046x over previous
//
#include <hip/hip_runtime.h>
#include <math.h>

// SoftGlidingBoxes: for each (b, ch=c*8+l) 256x256 image and scale s=1..8,
// sum over valid positions of the s x s sliding-window max, then relu(.)+1.
// x: [16, 256, 256, 3, 8] fp32 -> out: [16, 3, 8, 8] fp32.
//
// Round-7 = Round-6 + ONE change: the per-row __syncthreads() is replaced by
//   s_waitcnt lgkmcnt(0)  +  raw s_barrier
// __syncthreads() emits `s_waitcnt vmcnt(0) lgkmcnt(0)` before s_barrier,
// which drains the row r-2 register prefetch at every barrier and defeats
// the 1.5-iteration latency slack (R6: 880 cyc stall/row-iter ~ 1 HBM miss).
// The prefetch lands in VGPRs (not LDS), so only lgkmcnt(0) — making this
// thread's ds_writes visible before peers read them — is semantically needed.

namespace {
constexpr int Bn = 16, Hn = 256, Wn = 256, CHn = 24, Sn = 8;
constexpr int IT = 16;                     // output rows per band
constexpr int NBANDS = Hn / IT;            // 16
constexpr int BDIM = 256;                  // 8 ch x 32 strips = 4 waves
constexpr int NBLK = 3 * NBANDS * Bn;      // 768
// LDS: bf16 col-pair words, addr(chl, m) = chl*144 + m + 5*(m>>5), m<128.
// Compute reads (m=4*strip+k) hit all 32 banks <=2 lanes each: free (m136).
constexpr int LSTR = 144;
constexpr int LWORDS = 8 * LSTR;           // 1152 words per buffer (4.6 KB)
constexpr int OUT_N = Bn * CHn * Sn;       // 3072
}

__device__ __forceinline__ unsigned bf16pack2(float a, float b) {  // RTNE
  unsigned ua = __float_as_uint(a), ub = __float_as_uint(b);
  ua = (ua + 0x7FFFu + ((ua >> 16) & 1u)) >> 16;
  ub = (ub + 0x7FFFu + ((ub >> 16) & 1u)) & 0xFFFF0000u;
  return ua | ub;
}

// Barrier WITHOUT the vmcnt(0) drain __syncthreads would emit. lgkmcnt(0)
// guarantees this thread's ds_writes completed before it signals arrival;
// "memory" clobber pins LDS access ordering around the barrier.
__device__ __forceinline__ void row_barrier() {
  asm volatile("s_waitcnt lgkmcnt(0)" ::: "memory");
  __builtin_amdgcn_s_barrier();
}

__global__ __launch_bounds__(BDIM, 3) void sgb_main(const float* __restrict__ x,
                                                    float* __restrict__ accum) {
  __shared__ unsigned buf[2][LWORDS];

  // lin = (g/8)*24 + cg*8 + g%8, g = band*16 + b. All 3 cg-siblings of a
  // given g share lin%8 -> same XCD under round-robin -> L2 line sharing.
  const int lin = blockIdx.x;               // 0..767
  const int q   = lin / 24;                 // g/8
  const int rem = lin - q * 24;
  const int cg  = rem >> 3;                 // 0..2
  const int g   = q * 8 + (rem & 7);        // 0..255
  const int band = g >> 4;
  const int b    = g & 15;
  const int i0   = band * IT;
  const int tid  = threadIdx.x;

  // compute role: (chl, strip) — 8 local ch x 32 strips of 8 cols
  const int chl = tid >> 5, strip = tid & 31;
  const int ch  = cg * 8 + chl;
  const int rb0 = chl * LSTR;

  // staging role: col-pair m (cols 2m, 2m+1), ch quad h..h+3 (h = 0 or 4)
  const int m   = tid & 127;
  const int h   = (tid >> 7) * 4;
  const int wsw = m + 5 * (m >> 5);         // swizzled word offset

  float P[7][8];                            // prev-row M_1..M_7, own 8 cols
#pragma unroll
  for (int s = 0; s < 7; ++s)
#pragma unroll
    for (int j = 0; j < 8; ++j) P[s][j] = -INFINITY;
  float nbP[7];                             // prev-row M_s[col 8] halo cache
#pragma unroll
  for (int s = 0; s < 7; ++s) nbP[s] = -INFINITY;
  float acc[Sn];
#pragma unroll
  for (int s = 0; s < Sn; ++s) acc[s] = 0.f;

  const float* img = x + ((long)b * Hn) * (Wn * CHn) + cg * 8 + h;
  const int rhi = i0 + IT + 6;              // topmost consumed row

  // Prologue: row rhi -> buf[0]; row rhi-1 -> in-flight regs.
  float4 v0 = make_float4(0.f, 0.f, 0.f, 0.f);
  float4 v1 = make_float4(0.f, 0.f, 0.f, 0.f);  // row r-1 (written this iter)
  float4 n0 = v0, n1 = v1;                      // row r-2 (in flight)
  if (rhi < Hn) {
    const float* src = img + ((long)rhi * Wn + 2 * m) * CHn;
    const float4 a0 = reinterpret_cast<const float4*>(src)[0];
    const float4 a1 = reinterpret_cast<const float4*>(src + CHn)[0];
    unsigned* d = &buf[0][h * LSTR + wsw];
    d[0 * LSTR] = bf16pack2(a0.x, a1.x);
    d[1 * LSTR] = bf16pack2(a0.y, a1.y);
    d[2 * LSTR] = bf16pack2(a0.z, a1.z);
    d[3 * LSTR] = bf16pack2(a0.w, a1.w);
  }
  if (rhi - 1 >= 0 && rhi - 1 < Hn) {
    const float* src = img + ((long)(rhi - 1) * Wn + 2 * m) * CHn;
    v0 = reinterpret_cast<const float4*>(src)[0];
    v1 = reinterpret_cast<const float4*>(src + CHn)[0];
  }

  for (int idx = 0; idx < IT + 7; ++idx) {
    const int r  = rhi - idx;
    const int pb = idx & 1;
    row_barrier();                          // buf[pb] holds row r (no vm drain)

    // Issue load of row r-2 (consumed at iter idx+2) — ~1.5 iters of slack,
    // now actually preserved across the barrier.
    const bool do_load = (idx < IT + 5) && (unsigned)(r - 2) < (unsigned)Hn;
    if (do_load) {
      const float* src = img + ((long)(r - 2) * Wn + 2 * m) * CHn;
      n0 = reinterpret_cast<const float4*>(src)[0];
      n1 = reinterpret_cast<const float4*>(src + CHn)[0];
    }

    float cp[8];                            // M_1[r] at own 8 cols
    if (r < Hn) {
#pragma unroll
      for (int k = 0; k < 4; ++k) {
        const int c = 4 * strip + k;
        const unsigned d = buf[pb][rb0 + c + 5 * (c >> 5)];
        cp[2 * k]     = __uint_as_float(d << 16);
        cp[2 * k + 1] = __uint_as_float(d & 0xFFFF0000u);
      }
    } else {
#pragma unroll
      for (int k = 0; k < 8; ++k) cp[k] = -INFINITY;
    }

    const bool outrow = (r < i0 + IT);      // r >= i0 always holds
    if (outrow) {                           // s=1: all 256 window starts valid
      acc[0] += ((cp[0] + cp[1]) + (cp[2] + cp[3])) +
                ((cp[4] + cp[5]) + (cp[6] + cp[7]));
    }

#pragma unroll
    for (int s = 2; s <= Sn; ++s) {
      // col-8 halo = lane+1's col 0. strip 31's pull is garbage but lands
      // only in windows with j+s>8 == exactly the invalid ones -> masked.
      const float nbNew = __shfl_down(cp[0], 1);
      const float nbOld = nbP[s - 2];
      nbP[s - 2] = nbNew;
      float a = cp[0];                      // in-place rotation, no cc[] array
#pragma unroll
      for (int j = 0; j < 7; ++j) {
        const float t = cp[j + 1];
        cp[j] = fmaxf(fmaxf(a, t), fmaxf(P[s - 2][j], P[s - 2][j + 1]));
        P[s - 2][j] = a;
        a = t;
      }
      cp[7] = fmaxf(fmaxf(a, nbNew), fmaxf(P[s - 2][7], nbOld));
      P[s - 2][7] = a;

      if (outrow && (r + s <= Hn)) {
        float lo = 0.f, hi = 0.f;           // hi: windows spilling past col 8-s
#pragma unroll
        for (int j = 0; j < 8; ++j) {
          if (j <= 8 - s) lo += cp[j]; else hi += cp[j];
        }
        acc[s - 1] += lo + (strip == 31 ? 0.f : hi);
      }
    }

    // LDS-write row r-1 (regs loaded at iter idx-1) into buf[pb^1].
    const bool do_write = (idx < IT + 6) && (unsigned)(r - 1) < (unsigned)Hn;
    if (do_write) {
      unsigned* d = &buf[pb ^ 1][h * LSTR + wsw];
      d[0 * LSTR] = bf16pack2(v0.x, v1.x);
      d[1 * LSTR] = bf16pack2(v0.y, v1.y);
      d[2 * LSTR] = bf16pack2(v0.z, v1.z);
      d[3 * LSTR] = bf16pack2(v0.w, v1.w);
    }
    v0 = n0; v1 = n1;
  }

  // Reduce 32 strips per ch. Wave = 2 ch x 32 strips; xor<32 stays in-half.
#pragma unroll
  for (int s = 0; s < Sn; ++s) {
    float v = acc[s];
    v += __shfl_xor(v, 16);
    v += __shfl_xor(v, 8);
    v += __shfl_xor(v, 4);
    v += __shfl_xor(v, 2);
    v += __shfl_xor(v, 1);
    if (strip == 0) atomicAdd(&accum[(b * CHn + ch) * Sn + s], v);
  }
}

__global__ void sgb_finalize(float* __restrict__ out) {
  const int i = blockIdx.x * blockDim.x + threadIdx.x;
  if (i < OUT_N) out[i] = fmaxf(out[i], 0.f) + 1.f;
}

extern "C" void kernel_launch(void* const* d_in, const int* in_sizes, int n_in,
                              void* d_out, int out_size, void* d_ws, size_t ws_size,
                              hipStream_t stream) {
  (void)in_sizes; (void)n_in; (void)d_ws; (void)ws_size; (void)out_size;
  const float* x = (const float*)d_in[0];
  float* out = (float*)d_out;

  hipMemsetAsync(out, 0, OUT_N * sizeof(float), stream);
  sgb_main<<<dim3(NBLK), BDIM, 0, stream>>>(x, out);   // 768 blocks x 256 thr
  sgb_finalize<<<(OUT_N + 255) / 256, 256, 0, stream>>>(out);
}